// Round 1
// baseline (111.182 us; speedup 1.0000x reference)
//
#include <hip/hip_runtime.h>
#include <math.h>

#define N_INST 64
#define HW 64000        // 200*320 pixels
#define TP 64           // pixels per k_mask block
#define MASK_BLOCKS (HW / TP)   // 1000

__device__ __forceinline__ float sigmoidf_(float x) {
    return 1.0f / (1.0f + __expf(-x));
}

// -------- workspace layout (floats) --------
// [0, 4096)   OT[j][i]  (O transposed, staged by k_mask)

// K_O: fully fused relation-logit + O computation.
// Grid 64 blocks x 64 lanes. Block i, lane j computes BOTH logit[i][j] and
// logit[j][i] from the raw class tables, then O[i][j] = relu(sig-sig) locally.
//  - i-side table reads are wave-uniform -> scalar loads (s_load).
//  - j-side reads are gathers within one 320B table row per c -> ~5 cache
//    lines/wave, L1/L2-resident (tables are 80 KB each).
//  - Two independent accumulator chains (accIJ/accJI) give ILP to cover
//    L1/L2 latency in this 1-wave-per-block latency-bound kernel.
// Replaces the previous k_gather + k_pair + k_relu_R (3 dispatches -> 1).
__global__ __launch_bounds__(64) void k_O(const float* __restrict__ bbox,
                                          const int*   __restrict__ cls,
                                          const float* __restrict__ U_w,
                                          const float* __restrict__ V_w,
                                          const float* __restrict__ Wc_w,
                                          const float* __restrict__ P_w,
                                          float* __restrict__ O_out,
                                          float* __restrict__ OT_ws) {
    const int i = blockIdx.x;    // 0..63
    const int j = threadIdx.x;   // 0..63
    const int ci = cls[i] - 1;   // wave-uniform
    const int cj = cls[j] - 1;   // per-lane

    // ---- class-relation term, both directions ----
    float accIJ = 0.0f, accJI = 0.0f;
#pragma unroll 8
    for (int c = 0; c < 256; ++c) {
        float p  = P_w[c];
        float ui = U_w[c * 80 + ci];   // uniform -> s_load
        float vi = V_w[c * 80 + ci];   // uniform -> s_load
        float uj = U_w[c * 80 + cj];   // gather within 320B row
        float vj = V_w[c * 80 + cj];   // gather within 320B row
        float ai = fmaxf(ui, 0.0f) * p;
        float aj = fmaxf(uj, 0.0f) * p;
        accIJ = fmaf(ai, fmaxf(vj, 0.0f), accIJ);
        accJI = fmaf(aj, fmaxf(vi, 0.0f), accJI);
    }

    // ---- bbox geometry term, both directions ----
    float xmin_i = bbox[i * 5 + 1], ymin_i = bbox[i * 5 + 2];
    float xmax_i = bbox[i * 5 + 3], ymax_i = bbox[i * 5 + 4];
    float xmin_j = bbox[j * 5 + 1], ymin_j = bbox[j * 5 + 2];
    float xmax_j = bbox[j * 5 + 3], ymax_j = bbox[j * 5 + 4];
    float wi = xmax_i - xmin_i + 1.0f, hi = ymax_i - ymin_i + 1.0f;
    float wj = xmax_j - xmin_j + 1.0f, hj = ymax_j - ymin_j + 1.0f;
    float xci = xmin_i + 0.5f * wi, yci = ymin_i + 0.5f * hi;
    float xcj = xmin_j + 0.5f * wj, ycj = ymin_j + 0.5f * hj;

    // (i,j) direction: normalized by box i
    float dx_ij = -(xci - xcj) / wi;
    float dy_ij = -(yci - ycj) / hi;
    float dw_ij = __logf(wj / wi);
    float dh_ij = __logf(hj / hi);
    // (j,i) direction: normalized by box j
    float dx_ji = -(xcj - xci) / wj;
    float dy_ji = -(ycj - yci) / hj;
    float dw_ji = __logf(wi / wj);
    float dh_ji = __logf(hi / hj);

#pragma unroll 8
    for (int o = 0; o < 128; ++o) {
        float w0 = Wc_w[o * 4 + 0], w1 = Wc_w[o * 4 + 1];
        float w2 = Wc_w[o * 4 + 2], w3 = Wc_w[o * 4 + 3];
        float p  = P_w[256 + o];
        float sij = dx_ij * w0 + dy_ij * w1 + dw_ij * w2 + dh_ij * w3;
        float sji = dx_ji * w0 + dy_ji * w1 + dw_ji * w2 + dh_ji * w3;
        accIJ = fmaf(fmaxf(sij, 0.0f), p, accIJ);
        accJI = fmaf(fmaxf(sji, 0.0f), p, accJI);
    }

    // ---- O = relu(sigmoid(L) - sigmoid(L^T)), computed in-lane ----
    float r = fmaxf(sigmoidf_(accIJ) - sigmoidf_(accJI), 0.0f);
    O_out[i * 64 + j] = r;    // coalesced
    OT_ws[j * 64 + i] = r;    // scattered, 4096 floats total
}

// K3: fused mask update. Block = 64-pixel tile x all 64 instances.
// Phase 1: t = sigmoid(mask tile) into LDS (computed ONCE per pixel).
// Phase 2: each thread owns 4i x 4p micro-tile; per j: 2x ds_read_b128 + 16 FMA.
// Grid = 1000 blocks -> ~15.6 waves/CU.
__global__ __launch_bounds__(256) void k_mask(const float* __restrict__ mask,
                                              const float* __restrict__ OT,
                                              float* __restrict__ out) {
    __shared__ float t_lds[64][64];   // t[j][p_local]
    __shared__ float o_lds[64][64];   // O^T[j][i]
    const int tid = threadIdx.x;
    const int pbase = blockIdx.x * TP;

    // stage O^T (coalesced: 16 floats/thread)
#pragma unroll
    for (int k = 0; k < 16; ++k) {
        int idx = k * 256 + tid;
        ((float*)o_lds)[idx] = OT[idx];
    }
    // phase 1: sigmoid into LDS (coalesced mask reads)
    {
        const int j0 = tid >> 6;   // 0..3
        const int p  = tid & 63;
#pragma unroll
        for (int k = 0; k < 16; ++k) {
            int j = j0 * 16 + k;
            float m = mask[j * HW + pbase + p];
            t_lds[j][p] = sigmoidf_(m);
        }
    }
    __syncthreads();

    // phase 2
    const int pg = tid & 15;   // pixels pg*4 .. pg*4+3
    const int ig = tid >> 4;   // i = ig*4 .. ig*4+3
    float acc[4][4];
#pragma unroll
    for (int a = 0; a < 4; ++a)
#pragma unroll
        for (int b = 0; b < 4; ++b) acc[a][b] = 0.0f;

#pragma unroll 8
    for (int j = 0; j < 64; ++j) {
        float4 t4 = *(const float4*)&t_lds[j][pg * 4];
        float4 o4 = *(const float4*)&o_lds[j][ig * 4];
        acc[0][0] = fmaf(o4.x, t4.x, acc[0][0]);
        acc[0][1] = fmaf(o4.x, t4.y, acc[0][1]);
        acc[0][2] = fmaf(o4.x, t4.z, acc[0][2]);
        acc[0][3] = fmaf(o4.x, t4.w, acc[0][3]);
        acc[1][0] = fmaf(o4.y, t4.x, acc[1][0]);
        acc[1][1] = fmaf(o4.y, t4.y, acc[1][1]);
        acc[1][2] = fmaf(o4.y, t4.z, acc[1][2]);
        acc[1][3] = fmaf(o4.y, t4.w, acc[1][3]);
        acc[2][0] = fmaf(o4.z, t4.x, acc[2][0]);
        acc[2][1] = fmaf(o4.z, t4.y, acc[2][1]);
        acc[2][2] = fmaf(o4.z, t4.z, acc[2][2]);
        acc[2][3] = fmaf(o4.z, t4.w, acc[2][3]);
        acc[3][0] = fmaf(o4.w, t4.x, acc[3][0]);
        acc[3][1] = fmaf(o4.w, t4.y, acc[3][1]);
        acc[3][2] = fmaf(o4.w, t4.z, acc[3][2]);
        acc[3][3] = fmaf(o4.w, t4.w, acc[3][3]);
    }

    // epilogue: out[i][p] = m[i][p] * (1 - t[i][p] * w[i][p])
#pragma unroll
    for (int a = 0; a < 4; ++a) {
        const int i = ig * 4 + a;
        float4 ti = *(const float4*)&t_lds[i][pg * 4];
        float4 mi = *(const float4*)(mask + (size_t)i * HW + pbase + pg * 4);  // L1-hot
        float4 r;
        r.x = mi.x * (1.0f - ti.x * acc[a][0]);
        r.y = mi.y * (1.0f - ti.y * acc[a][1]);
        r.z = mi.z * (1.0f - ti.z * acc[a][2]);
        r.w = mi.w * (1.0f - ti.w * acc[a][3]);
        *(float4*)(out + (size_t)i * HW + pbase + pg * 4) = r;
    }
}

extern "C" void kernel_launch(void* const* d_in, const int* in_sizes, int n_in,
                              void* d_out, int out_size, void* d_ws, size_t ws_size,
                              hipStream_t stream) {
    const float* mask = (const float*)d_in[0];
    const float* bbox = (const float*)d_in[1];
    const int*   cls  = (const int*)d_in[2];
    const float* U_w  = (const float*)d_in[3];
    const float* V_w  = (const float*)d_in[4];
    const float* Wc_w = (const float*)d_in[5];
    const float* P_w  = (const float*)d_in[6];

    float* out_mask = (float*)d_out;                         // 4,096,000 floats
    float* out_O    = (float*)d_out + (size_t)N_INST * HW;   // 4096 floats

    float* ws = (float*)d_ws;
    float* OT = ws;              // 4096 floats

    k_O<<<64, 64, 0, stream>>>(bbox, cls, U_w, V_w, Wc_w, P_w, out_O, OT);
    k_mask<<<MASK_BLOCKS, 256, 0, stream>>>(mask, OT, out_mask);
}

// Round 2
// 106.064 us; speedup vs baseline: 1.0483x; 1.0483x over previous
//
#include <hip/hip_runtime.h>
#include <math.h>

#define N_INST 64
#define HW 64000        // 200*320 pixels
#define TP 64           // pixels per k_mask block
#define MASK_BLOCKS (HW / TP)   // 1000

__device__ __forceinline__ float sigmoidf_(float x) {
    return 1.0f / (1.0f + __expf(-x));
}

// -------- workspace layout (floats) --------
// [0,     4096)   OT[j][i]   (O transposed, for k_mask's coalesced staging)
// [4096,  20480)  AT[c][j] = relu(U[c][cls_j-1]) * P[c]   (256 x 64)
// [20480, 36864)  BT[c][j] = relu(V[c][cls_j-1])          (256 x 64)

// K0: gather per-instance class columns into dense TRANSPOSED layouts.
// grid 64 x 256: global thread t covers (c = t>>6, j = t&63); each wave has
// uniform c, per-lane j -> gather within one 320B table row (~5 lines/wave),
// write coalesced. 2 gathers/thread, 32K gathers total (done ONCE -- the R1
// fused version redid these per-lane in the hot loop and lost 9us).
__global__ __launch_bounds__(256) void k_gatherT(const int* __restrict__ cls,
                                                 const float* __restrict__ U_w,
                                                 const float* __restrict__ V_w,
                                                 const float* __restrict__ P_w,
                                                 float* __restrict__ AT,
                                                 float* __restrict__ BT) {
    const int tid = threadIdx.x;             // 0..255
    const int c = blockIdx.x * 4 + (tid >> 6);  // 0..255, wave-uniform
    const int j = tid & 63;                  // per-lane
    const int cj = cls[j] - 1;
    const float p = P_w[c];                  // uniform -> s_load
    float u = U_w[c * 80 + cj];
    float v = V_w[c * 80 + cj];
    AT[c * 64 + j] = fmaxf(u, 0.0f) * p;
    BT[c * 64 + j] = fmaxf(v, 0.0f);
}

// K1: block i, lane j computes BOTH logit[i][j] and logit[j][i] from the
// dense tables, then O[i][j] = relu(sig - sig) in-lane.
//   logit[i][j] class term: AT[c][i] (uniform s_load) * BT[c][j] (coalesced)
//   logit[j][i] class term: AT[c][j] (coalesced)      * BT[c][i] (uniform)
// Two independent acc chains give ILP. Replaces k_pair + k_relu_R.
__global__ __launch_bounds__(64) void k_O2(const float* __restrict__ bbox,
                                           const float* __restrict__ AT,
                                           const float* __restrict__ BT,
                                           const float* __restrict__ Wc_w,
                                           const float* __restrict__ P_w,
                                           float* __restrict__ O_out,
                                           float* __restrict__ OT_ws) {
    const int i = blockIdx.x;    // 0..63
    const int j = threadIdx.x;   // 0..63

    float accIJ = 0.0f, accJI = 0.0f;
#pragma unroll 16
    for (int c = 0; c < 256; ++c) {
        const float at_i = AT[c * 64 + i];   // uniform -> s_load
        const float bt_i = BT[c * 64 + i];   // uniform -> s_load
        const float at_j = AT[c * 64 + j];   // coalesced 256B vload
        const float bt_j = BT[c * 64 + j];   // coalesced 256B vload
        accIJ = fmaf(at_i, bt_j, accIJ);
        accJI = fmaf(at_j, bt_i, accJI);
    }

    // ---- bbox geometry term, both directions ----
    float xmin_i = bbox[i * 5 + 1], ymin_i = bbox[i * 5 + 2];
    float xmax_i = bbox[i * 5 + 3], ymax_i = bbox[i * 5 + 4];
    float xmin_j = bbox[j * 5 + 1], ymin_j = bbox[j * 5 + 2];
    float xmax_j = bbox[j * 5 + 3], ymax_j = bbox[j * 5 + 4];
    float wi = xmax_i - xmin_i + 1.0f, hi = ymax_i - ymin_i + 1.0f;
    float wj = xmax_j - xmin_j + 1.0f, hj = ymax_j - ymin_j + 1.0f;
    float xci = xmin_i + 0.5f * wi, yci = ymin_i + 0.5f * hi;
    float xcj = xmin_j + 0.5f * wj, ycj = ymin_j + 0.5f * hj;

    float dx_ij = -(xci - xcj) / wi;
    float dy_ij = -(yci - ycj) / hi;
    float dw_ij = __logf(wj / wi);
    float dh_ij = __logf(hj / hi);
    float dx_ji = -(xcj - xci) / wj;
    float dy_ji = -(ycj - yci) / hj;
    float dw_ji = __logf(wi / wj);
    float dh_ji = __logf(hi / hj);

#pragma unroll 8
    for (int o = 0; o < 128; ++o) {
        float w0 = Wc_w[o * 4 + 0], w1 = Wc_w[o * 4 + 1];
        float w2 = Wc_w[o * 4 + 2], w3 = Wc_w[o * 4 + 3];
        float p  = P_w[256 + o];
        float sij = dx_ij * w0 + dy_ij * w1 + dw_ij * w2 + dh_ij * w3;
        float sji = dx_ji * w0 + dy_ji * w1 + dw_ji * w2 + dh_ji * w3;
        accIJ = fmaf(fmaxf(sij, 0.0f), p, accIJ);
        accJI = fmaf(fmaxf(sji, 0.0f), p, accJI);
    }

    float r = fmaxf(sigmoidf_(accIJ) - sigmoidf_(accJI), 0.0f);
    O_out[i * 64 + j] = r;    // coalesced
    OT_ws[j * 64 + i] = r;    // scattered, 4096 floats total
}

// K2: fused mask update. Block = 64-pixel tile x all 64 instances.
// Phase 1: t = sigmoid(mask tile) into LDS (computed ONCE per pixel).
// Phase 2: each thread owns 4i x 4p micro-tile; per j: 2x ds_read_b128 + 16 FMA.
// Grid = 1000 blocks -> ~4 blocks/CU, 16 waves/CU.
__global__ __launch_bounds__(256) void k_mask(const float* __restrict__ mask,
                                              const float* __restrict__ OT,
                                              float* __restrict__ out) {
    __shared__ float t_lds[64][64];   // t[j][p_local]
    __shared__ float o_lds[64][64];   // O^T[j][i]
    const int tid = threadIdx.x;
    const int pbase = blockIdx.x * TP;

    // stage O^T (coalesced: 16 floats/thread)
#pragma unroll
    for (int k = 0; k < 16; ++k) {
        int idx = k * 256 + tid;
        ((float*)o_lds)[idx] = OT[idx];
    }
    // phase 1: sigmoid into LDS (coalesced mask reads)
    {
        const int j0 = tid >> 6;   // 0..3
        const int p  = tid & 63;
#pragma unroll
        for (int k = 0; k < 16; ++k) {
            int j = j0 * 16 + k;
            float m = mask[j * HW + pbase + p];
            t_lds[j][p] = sigmoidf_(m);
        }
    }
    __syncthreads();

    // phase 2
    const int pg = tid & 15;   // pixels pg*4 .. pg*4+3
    const int ig = tid >> 4;   // i = ig*4 .. ig*4+3
    float acc[4][4];
#pragma unroll
    for (int a = 0; a < 4; ++a)
#pragma unroll
        for (int b = 0; b < 4; ++b) acc[a][b] = 0.0f;

#pragma unroll 8
    for (int j = 0; j < 64; ++j) {
        float4 t4 = *(const float4*)&t_lds[j][pg * 4];
        float4 o4 = *(const float4*)&o_lds[j][ig * 4];
        acc[0][0] = fmaf(o4.x, t4.x, acc[0][0]);
        acc[0][1] = fmaf(o4.x, t4.y, acc[0][1]);
        acc[0][2] = fmaf(o4.x, t4.z, acc[0][2]);
        acc[0][3] = fmaf(o4.x, t4.w, acc[0][3]);
        acc[1][0] = fmaf(o4.y, t4.x, acc[1][0]);
        acc[1][1] = fmaf(o4.y, t4.y, acc[1][1]);
        acc[1][2] = fmaf(o4.y, t4.z, acc[1][2]);
        acc[1][3] = fmaf(o4.y, t4.w, acc[1][3]);
        acc[2][0] = fmaf(o4.z, t4.x, acc[2][0]);
        acc[2][1] = fmaf(o4.z, t4.y, acc[2][1]);
        acc[2][2] = fmaf(o4.z, t4.z, acc[2][2]);
        acc[2][3] = fmaf(o4.z, t4.w, acc[2][3]);
        acc[3][0] = fmaf(o4.w, t4.x, acc[3][0]);
        acc[3][1] = fmaf(o4.w, t4.y, acc[3][1]);
        acc[3][2] = fmaf(o4.w, t4.z, acc[3][2]);
        acc[3][3] = fmaf(o4.w, t4.w, acc[3][3]);
    }

    // epilogue: out[i][p] = m[i][p] * (1 - t[i][p] * w[i][p])
#pragma unroll
    for (int a = 0; a < 4; ++a) {
        const int i = ig * 4 + a;
        float4 ti = *(const float4*)&t_lds[i][pg * 4];
        float4 mi = *(const float4*)(mask + (size_t)i * HW + pbase + pg * 4);  // L1-hot
        float4 r;
        r.x = mi.x * (1.0f - ti.x * acc[a][0]);
        r.y = mi.y * (1.0f - ti.y * acc[a][1]);
        r.z = mi.z * (1.0f - ti.z * acc[a][2]);
        r.w = mi.w * (1.0f - ti.w * acc[a][3]);
        *(float4*)(out + (size_t)i * HW + pbase + pg * 4) = r;
    }
}

extern "C" void kernel_launch(void* const* d_in, const int* in_sizes, int n_in,
                              void* d_out, int out_size, void* d_ws, size_t ws_size,
                              hipStream_t stream) {
    const float* mask = (const float*)d_in[0];
    const float* bbox = (const float*)d_in[1];
    const int*   cls  = (const int*)d_in[2];
    const float* U_w  = (const float*)d_in[3];
    const float* V_w  = (const float*)d_in[4];
    const float* Wc_w = (const float*)d_in[5];
    const float* P_w  = (const float*)d_in[6];

    float* out_mask = (float*)d_out;                         // 4,096,000 floats
    float* out_O    = (float*)d_out + (size_t)N_INST * HW;   // 4096 floats

    float* ws = (float*)d_ws;
    float* OT = ws;              // 4096
    float* AT = ws + 4096;       // 16384
    float* BT = ws + 20480;      // 16384

    k_gatherT<<<64, 256, 0, stream>>>(cls, U_w, V_w, P_w, AT, BT);
    k_O2<<<64, 64, 0, stream>>>(bbox, AT, BT, Wc_w, P_w, out_O, ws /*OT*/);
    k_mask<<<MASK_BLOCKS, 256, 0, stream>>>(mask, ws /*OT*/, out_mask);
}

// Round 3
// 96.306 us; speedup vs baseline: 1.1545x; 1.1013x over previous
//
#include <hip/hip_runtime.h>
#include <math.h>

#define N_INST 64
#define HW 64000        // 200*320 pixels
#define TP 64           // pixels per k_mask block
#define MASK_BLOCKS (HW / TP)   // 1000

__device__ __forceinline__ float sigmoidf_(float x) {
    return 1.0f / (1.0f + __expf(-x));
}

// -------- workspace layout (floats) --------
// [0,     4096)   logit[i][j]
// [4096,  20480)  Afp[i][c] = relu(U[c][cls_i-1]) * P[c]   (64 x 256)
// [20480, 36864)  BfT[c][j] = relu(V[c][cls_j-1])          (256 x 64)

// K0: gather per-instance class columns into dense, matmul-friendly layouts.
// grid 64 x 256. Block b: Afp row b (lanes = c) and BfT rows 4b..4b+3.
// (proven round-0 kernel, unchanged)
__global__ void k_gather(const int* __restrict__ cls,
                         const float* __restrict__ U_w,
                         const float* __restrict__ V_w,
                         const float* __restrict__ P_w,
                         float* __restrict__ Afp,
                         float* __restrict__ BfT) {
    const int b = blockIdx.x;     // 0..63
    const int tid = threadIdx.x;  // 0..255
    // Afp[b][tid]: cls[b] is wave-uniform; gather stride-320B, write coalesced.
    const int cb = cls[b] - 1;
    float u = U_w[tid * 80 + cb];
    Afp[b * 256 + tid] = fmaxf(u, 0.0f) * P_w[tid];
    // BfT[c][j] for c = 4b + tid/64: per-lane gather on cls[j], write coalesced.
    const int c = b * 4 + (tid >> 6);
    const int j = tid & 63;
    const int cj = cls[j] - 1;
    float v = V_w[c * 80 + cj];
    BfT[c * 64 + j] = fmaxf(v, 0.0f);
}

// K1: logit[i][j], 4 waves per block (vs 1 in round 0 -- same total work,
// 4x parallelism on the latency-bound load chain). Wave w covers c in
// [64w, 64w+64) of the class term and o in [32w, 32w+32) of the geometry
// term; partials summed through 1KB LDS by wave 0.
__global__ __launch_bounds__(256) void k_pair(const float* __restrict__ bbox,
                                              const float* __restrict__ Afp,
                                              const float* __restrict__ BfT,
                                              const float* __restrict__ Wc_w,
                                              const float* __restrict__ P_w,
                                              float* __restrict__ logit) {
    __shared__ float part[4][64];
    const int i = blockIdx.x;
    const int j = threadIdx.x & 63;
    const int w = threadIdx.x >> 6;

    // class term: 64 c's per wave; Afp row i wave-uniform -> s_load,
    // BfT row coalesced vload.
    const float* __restrict__ ai = Afp + i * 256 + w * 64;
    const float* __restrict__ bt = BfT + (w * 64) * 64;
    float acc = 0.0f;
#pragma unroll 16
    for (int c = 0; c < 64; ++c) {
        acc = fmaf(ai[c], bt[c * 64 + j], acc);
    }

    // bbox geometry term (i-side wave-uniform); each wave does 32 of 128 o's.
    float xmin_i = bbox[i * 5 + 1], ymin_i = bbox[i * 5 + 2];
    float xmax_i = bbox[i * 5 + 3], ymax_i = bbox[i * 5 + 4];
    float xmin_j = bbox[j * 5 + 1], ymin_j = bbox[j * 5 + 2];
    float xmax_j = bbox[j * 5 + 3], ymax_j = bbox[j * 5 + 4];
    float wi = xmax_i - xmin_i + 1.0f, hi = ymax_i - ymin_i + 1.0f;
    float wj = xmax_j - xmin_j + 1.0f, hj = ymax_j - ymin_j + 1.0f;
    float xci = xmin_i + 0.5f * wi, yci = ymin_i + 0.5f * hi;
    float xcj = xmin_j + 0.5f * wj, ycj = ymin_j + 0.5f * hj;
    float dx = -(xci - xcj) / wi;
    float dy = -(yci - ycj) / hi;
    float dw = __logf(wj / wi);
    float dh = __logf(hj / hi);

    const float* __restrict__ wc = Wc_w + w * 32 * 4;
    const float* __restrict__ pg = P_w + 256 + w * 32;
#pragma unroll 8
    for (int oo = 0; oo < 32; ++oo) {
        float s = dx * wc[oo * 4 + 0] + dy * wc[oo * 4 + 1]
                + dw * wc[oo * 4 + 2] + dh * wc[oo * 4 + 3];
        s = fmaxf(s, 0.0f);
        acc = fmaf(s, pg[oo], acc);
    }

    part[w][j] = acc;   // bank (64w+j)%32 -> 2-way, free
    __syncthreads();
    if (threadIdx.x < 64) {
        logit[i * 64 + j] = part[0][j] + part[1][j] + part[2][j] + part[3][j];
    }
}

// K2: fused O-compute + mask update (absorbs round-0's k_relu_R).
// Stage logit into padded LDS, compute O = relu(sig(L)-sig(L^T)) in-block
// (redundant across blocks but trans-pipe cheap and hidden under HBM
// streaming); block 0 also writes the O output. Then the proven round-0
// mask-update phases.
__global__ __launch_bounds__(256) void k_mask(const float* __restrict__ mask,
                                              const float* __restrict__ logit,
                                              float* __restrict__ O_out,
                                              float* __restrict__ out) {
    __shared__ float t_lds[64][64];   // t[j][p_local] = sigmoid(mask)
    __shared__ float l_lds[64][65];   // logit, padded: transpose read = 2-way
    __shared__ float o_lds[64][64];   // O^T[j][i]
    const int tid = threadIdx.x;
    const int pbase = blockIdx.x * TP;

    // stage logit (coalesced: 16 floats/thread)
#pragma unroll
    for (int k = 0; k < 16; ++k) {
        int idx = k * 256 + tid;
        l_lds[idx >> 6][idx & 63] = logit[idx];
    }
    // phase 1: sigmoid(mask tile) into LDS (coalesced mask reads)
    {
        const int j0 = tid >> 6;   // 0..3
        const int p  = tid & 63;
#pragma unroll
        for (int k = 0; k < 16; ++k) {
            int j = j0 * 16 + k;
            float m = mask[j * HW + pbase + p];
            t_lds[j][p] = sigmoidf_(m);
        }
    }
    __syncthreads();

    // O^T[j][i] = relu(sig(L[i][j]) - sig(L[j][i])); 16 entries/thread.
    // l_lds[i][j]: addr = 65i+j, i = lane -> banks (i+j)%32, 2-way, free.
    const bool write_O = (blockIdx.x == 0);
#pragma unroll
    for (int k = 0; k < 16; ++k) {
        int idx = k * 256 + tid;
        int jj = idx >> 6;         // wave-uniform
        int ii = idx & 63;         // lane
        float r = sigmoidf_(l_lds[ii][jj]) - sigmoidf_(l_lds[jj][ii]);
        r = fmaxf(r, 0.0f);
        o_lds[jj][ii] = r;
        if (write_O) O_out[ii * 64 + jj] = r;   // block 0 only, off critical path
    }
    __syncthreads();

    // phase 2: each thread owns 4i x 4p micro-tile
    const int pg = tid & 15;   // pixels pg*4 .. pg*4+3
    const int ig = tid >> 4;   // i = ig*4 .. ig*4+3
    float acc[4][4];
#pragma unroll
    for (int a = 0; a < 4; ++a)
#pragma unroll
        for (int b = 0; b < 4; ++b) acc[a][b] = 0.0f;

#pragma unroll 8
    for (int j = 0; j < 64; ++j) {
        float4 t4 = *(const float4*)&t_lds[j][pg * 4];
        float4 o4 = *(const float4*)&o_lds[j][ig * 4];
        acc[0][0] = fmaf(o4.x, t4.x, acc[0][0]);
        acc[0][1] = fmaf(o4.x, t4.y, acc[0][1]);
        acc[0][2] = fmaf(o4.x, t4.z, acc[0][2]);
        acc[0][3] = fmaf(o4.x, t4.w, acc[0][3]);
        acc[1][0] = fmaf(o4.y, t4.x, acc[1][0]);
        acc[1][1] = fmaf(o4.y, t4.y, acc[1][1]);
        acc[1][2] = fmaf(o4.y, t4.z, acc[1][2]);
        acc[1][3] = fmaf(o4.y, t4.w, acc[1][3]);
        acc[2][0] = fmaf(o4.z, t4.x, acc[2][0]);
        acc[2][1] = fmaf(o4.z, t4.y, acc[2][1]);
        acc[2][2] = fmaf(o4.z, t4.z, acc[2][2]);
        acc[2][3] = fmaf(o4.z, t4.w, acc[2][3]);
        acc[3][0] = fmaf(o4.w, t4.x, acc[3][0]);
        acc[3][1] = fmaf(o4.w, t4.y, acc[3][1]);
        acc[3][2] = fmaf(o4.w, t4.z, acc[3][2]);
        acc[3][3] = fmaf(o4.w, t4.w, acc[3][3]);
    }

    // epilogue: out[i][p] = m[i][p] * (1 - t[i][p] * w[i][p])
#pragma unroll
    for (int a = 0; a < 4; ++a) {
        const int i = ig * 4 + a;
        float4 ti = *(const float4*)&t_lds[i][pg * 4];
        float4 mi = *(const float4*)(mask + (size_t)i * HW + pbase + pg * 4);  // L1-hot
        float4 r;
        r.x = mi.x * (1.0f - ti.x * acc[a][0]);
        r.y = mi.y * (1.0f - ti.y * acc[a][1]);
        r.z = mi.z * (1.0f - ti.z * acc[a][2]);
        r.w = mi.w * (1.0f - ti.w * acc[a][3]);
        *(float4*)(out + (size_t)i * HW + pbase + pg * 4) = r;
    }
}

extern "C" void kernel_launch(void* const* d_in, const int* in_sizes, int n_in,
                              void* d_out, int out_size, void* d_ws, size_t ws_size,
                              hipStream_t stream) {
    const float* mask = (const float*)d_in[0];
    const float* bbox = (const float*)d_in[1];
    const int*   cls  = (const int*)d_in[2];
    const float* U_w  = (const float*)d_in[3];
    const float* V_w  = (const float*)d_in[4];
    const float* Wc_w = (const float*)d_in[5];
    const float* P_w  = (const float*)d_in[6];

    float* out_mask = (float*)d_out;                         // 4,096,000 floats
    float* out_O    = (float*)d_out + (size_t)N_INST * HW;   // 4096 floats

    float* ws    = (float*)d_ws;
    float* logit = ws;           // 4096
    float* Afp   = ws + 4096;    // 16384
    float* BfT   = ws + 20480;   // 16384

    k_gather<<<64, 256, 0, stream>>>(cls, U_w, V_w, P_w, Afp, BfT);
    k_pair<<<64, 256, 0, stream>>>(bbox, Afp, BfT, Wc_w, P_w, logit);
    k_mask<<<MASK_BLOCKS, 256, 0, stream>>>(mask, logit, out_O, out_mask);
}